// Round 4
// baseline (2610.249 us; speedup 1.0000x reference)
//
#include <hip/hip_runtime.h>
#include <hip/hip_fp16.h>
#include <cstdint>
#include <cmath>

#define EPSLN 1e-5f
#define NPB 256          // src nodes per coarse bucket (power of 2)
#define NPB_SHIFT 8
#define MAXB 1024        // max coarse buckets (N <= 262144)
#define TILE 16384       // edges per sort tile (LDS staging = 64KB)
#define SRC_BITS 18      // low-field width in packed word (dst: 18 bits)
#define DST_MASK 0x3FFFF
#define FCAP 17664       // k_fine LDS staging words; >= CAP
#define FK 35            // FCAP / 512 rounded up
#define PSH 11           // dst-partition shift: 2048 dst nodes / partition
#define PLOC 2048        // dst nodes per partition
#define PMSK 2047
#define PMAXC 128        // max partitions (N <= 262144 -> <= 128)
#define NSPL 4           // splits per partition (conv/deg grid.y)

// ---------------------------------------------------------------------------
// Init per-bucket and per-partition global cursors.
// ---------------------------------------------------------------------------
__global__ __launch_bounds__(512) void k_init(int* __restrict__ bcur, int B, int cap,
                                              int* __restrict__ pcur, int P, int pcap) {
    int i = blockIdx.x * 512 + threadIdx.x;
    if (i < B) bcur[i] = i * cap;
    if (i < P) pcur[i] = i * pcap;
}

// ---------------------------------------------------------------------------
// Coarse scatter: bucket by SRC>>8 (round-0 proven machinery, new key).
// payload w = (src&255)<<18 | dst.
// ---------------------------------------------------------------------------
__global__ __launch_bounds__(512) void k_scatter(const int* __restrict__ src,
                                                 const int* __restrict__ dst,
                                                 int* __restrict__ bcur,
                                                 unsigned* __restrict__ packed,
                                                 int E, int B) {
    __shared__ unsigned stg[TILE];     // 64 KB staging
    __shared__ int hist[MAXB];         // counts, then reused as gbase
    __shared__ int lbase[MAXB + 1];    // exclusive scan (local segment bases)
    __shared__ int sm[MAXB];           // scan workspace
    int tid = threadIdx.x;
    int i0 = tid, i1 = tid + 512;
    hist[i0] = 0; hist[i1] = 0;
    __syncthreads();

    int beg = blockIdx.x * TILE;
    int end = min(beg + TILE, E);
    int cnt = end - beg;

    unsigned w[32];   // packed payload words
    unsigned m[32];   // meta: (bkt<<14)|rank, 0xFFFFFFFF = invalid

    // Phase A: load + histogram + rank (single pass over src/dst)
    if (cnt == TILE && ((E & 3) == 0)) {
        const int4* d4 = (const int4*)(dst + beg);
        const int4* s4 = (const int4*)(src + beg);
#pragma unroll
        for (int k = 0; k < 8; ++k) {
            int4 d = d4[tid + k * 512];
            int4 s = s4[tid + k * 512];
            int b0 = s.x >> NPB_SHIFT, b1 = s.y >> NPB_SHIFT;
            int b2 = s.z >> NPB_SHIFT, b3 = s.w >> NPB_SHIFT;
            int r0 = atomicAdd(&hist[b0], 1);
            int r1 = atomicAdd(&hist[b1], 1);
            int r2 = atomicAdd(&hist[b2], 1);
            int r3 = atomicAdd(&hist[b3], 1);
            w[4 * k + 0] = ((unsigned)(s.x & (NPB - 1)) << SRC_BITS) | (unsigned)d.x;
            w[4 * k + 1] = ((unsigned)(s.y & (NPB - 1)) << SRC_BITS) | (unsigned)d.y;
            w[4 * k + 2] = ((unsigned)(s.z & (NPB - 1)) << SRC_BITS) | (unsigned)d.z;
            w[4 * k + 3] = ((unsigned)(s.w & (NPB - 1)) << SRC_BITS) | (unsigned)d.w;
            m[4 * k + 0] = ((unsigned)b0 << 14) | (unsigned)r0;
            m[4 * k + 1] = ((unsigned)b1 << 14) | (unsigned)r1;
            m[4 * k + 2] = ((unsigned)b2 << 14) | (unsigned)r2;
            m[4 * k + 3] = ((unsigned)b3 << 14) | (unsigned)r3;
        }
    } else {
#pragma unroll
        for (int k = 0; k < 32; ++k) {
            int i = beg + tid + k * 512;
            if (i < end) {
                int d = dst[i];
                int s = src[i];
                int bkt = s >> NPB_SHIFT;
                int r = atomicAdd(&hist[bkt], 1);
                w[k] = ((unsigned)(s & (NPB - 1)) << SRC_BITS) | (unsigned)d;
                m[k] = ((unsigned)bkt << 14) | (unsigned)r;
            } else {
                m[k] = 0xFFFFFFFFu;
            }
        }
    }
    __syncthreads();

    // Phase B: scan counts -> lbase; reserve global chunks (gbase into hist)
    int v0 = hist[i0], v1 = hist[i1];
    sm[i0] = v0; sm[i1] = v1;
    __syncthreads();
    for (int off = 1; off < MAXB; off <<= 1) {
        int t0 = (i0 >= off) ? sm[i0 - off] : 0;
        int t1 = (i1 >= off) ? sm[i1 - off] : 0;
        __syncthreads();
        sm[i0] += t0; sm[i1] += t1;
        __syncthreads();
    }
    lbase[i0] = sm[i0] - v0;
    lbase[i1] = sm[i1] - v1;
    if (i0 < B) hist[i0] = v0 ? atomicAdd(&bcur[i0], v0) : 0;
    if (i1 < B) hist[i1] = v1 ? atomicAdd(&bcur[i1], v1) : 0;
    if (tid == 0) lbase[B] = cnt;
    __syncthreads();

    // Phase C: place into staging (no atomics; rank precomputed)
#pragma unroll
    for (int k = 0; k < 32; ++k) {
        if (m[k] != 0xFFFFFFFFu) {
            int bkt = (int)(m[k] >> 14);
            int r   = (int)(m[k] & 16383u);
            stg[lbase[bkt] + r] = w[k];
        }
    }
    __syncthreads();

    // Phase D: per-wave bucket-range drain
    int wv = tid >> 6;
    int ln = tid & 63;
    for (int b = wv; b < B; b += 8) {
        int lb = lbase[b];
        int le = lbase[b + 1];
        int gb = hist[b];
        for (int j = lb + ln; j < le; j += 64)
            packed[gb + (j - lb)] = stg[j];
    }
}

// ---------------------------------------------------------------------------
// Fine pass: per src-bucket, sort edges by dst-partition (dst>>11), emit
// (src<<11)|dst_local words into a PARTITION-MAJOR global edge list.
// Runs of ~E/(B*P) edges share one 256-src (4KB) gather window -> conv
// gathers become L1-windowed instead of fully random.
// ---------------------------------------------------------------------------
__global__ __launch_bounds__(512) void k_fine(const int* __restrict__ bcur,
                                              const unsigned* __restrict__ packed,
                                              unsigned* __restrict__ elist,
                                              int* __restrict__ pcur,
                                              int cap, int pcap, int pcnt) {
    __shared__ unsigned stg[FCAP];   // ~69 KB part-sorted staging
    __shared__ int hist[PMAXC];
    __shared__ int exs[PMAXC];
    __shared__ int gbs[PMAXC];
    int b = blockIdx.x;
    int tid = threadIdx.x;
    int beg = b * cap;
    int cnt = min(bcur[b] - beg, FCAP);
    if (tid < PMAXC) hist[tid] = 0;
    __syncthreads();

    // Pass A: load bucket words into VGPRs + partition histogram w/ rank
    unsigned w[FK];
    int r[FK];
#pragma unroll
    for (int k = 0; k < FK; ++k) {
        int i = tid + k * 512;
        if (i < cnt) {
            w[k] = packed[beg + i];
            int part = (int)((w[k] & DST_MASK) >> PSH);
            r[k] = atomicAdd(&hist[part], 1);
        }
    }
    __syncthreads();

    // Pass B: 128-entry scan -> exclusive bases; reserve global part space
    int hv = 0;
    if (tid < PMAXC) { hv = hist[tid]; exs[tid] = hv; }
    __syncthreads();
    for (int off = 1; off < PMAXC; off <<= 1) {
        int t = 0;
        if (tid < PMAXC && tid >= off) t = exs[tid - off];
        __syncthreads();
        if (tid < PMAXC) exs[tid] += t;
        __syncthreads();
    }
    if (tid < PMAXC) {
        exs[tid] -= hv;   // exclusive base
        gbs[tid] = (tid < pcnt && hv) ? atomicAdd(&pcur[tid], hv) : 0;
    }
    __syncthreads();

    // Pass C: atomic-free LDS scatter, emitting transformed words
    unsigned bb = (unsigned)b << NPB_SHIFT;
#pragma unroll
    for (int k = 0; k < FK; ++k) {
        int i = tid + k * 512;
        if (i < cnt) {
            unsigned wd = w[k];
            int part = (int)((wd & DST_MASK) >> PSH);
            unsigned ew = ((bb | (wd >> SRC_BITS)) << PSH) | (wd & PMSK);
            stg[exs[part] + r[k]] = ew;
        }
    }
    __syncthreads();

    // Pass D: per-wave partition drain into partition-major elist
    int wv = tid >> 6, ln = tid & 63;
    for (int p = wv; p < pcnt; p += 8) {
        int lb = exs[p], len = hist[p], gb = gbs[p];
        int lim = (p + 1) * pcap;
        for (int j = ln; j < len; j += 64) {
            int gi = gb + j;
            if (gi < lim) elist[gi] = stg[lb + j];
        }
    }
}

// ---------------------------------------------------------------------------
// Degree count: per (partition, split) block, LDS counters, partials out.
// ---------------------------------------------------------------------------
__global__ __launch_bounds__(512) void k_deg(const int* __restrict__ pcur,
                                             const unsigned* __restrict__ elist,
                                             int* __restrict__ pdeg,
                                             int pcap, int pszn) {
    int p = blockIdx.x, s = blockIdx.y, S = gridDim.y;
    int tid = threadIdx.x;
    __shared__ int cnt[PLOC];
    for (int t = tid; t < PLOC; t += 512) cnt[t] = 0;
    __syncthreads();
    int base = p * pcap;
    int n = min(pcur[p] - base, pcap);
    int lo = (int)((long long)n * s / S), hi = (int)((long long)n * (s + 1) / S);
    for (int j = base + lo + tid; j < base + hi; j += 512)
        atomicAdd(&cnt[elist[j] & PMSK], 1);
    __syncthreads();
    int* dst = pdeg + (size_t)s * pszn + ((size_t)p << PSH);
    for (int t = tid; t < PLOC; t += 512) dst[t] = cnt[t];
}

// ---------------------------------------------------------------------------
// Degree finalize: dinv/sqd + pre-scaled node features xs3 [N,4].
// ---------------------------------------------------------------------------
__global__ __launch_bounds__(512) void k_fdeg(const int* __restrict__ pdeg,
                                              const float* __restrict__ node,
                                              float* __restrict__ dinv,
                                              float* __restrict__ sqd,
                                              float* __restrict__ xs3,
                                              int N, int pszn, int S) {
    int v = blockIdx.x * 512 + threadIdx.x;
    if (v >= N) return;
    int d = 0;
    for (int s = 0; s < S; ++s) d += pdeg[(size_t)s * pszn + v];
    float c = (float)(d + 1);      // +1: self-loop
    float di = rsqrtf(c);
    dinv[v] = di;
    sqd[v] = sqrtf(c);
    xs3[(size_t)v * 4 + 0] = di * node[(size_t)v * 3 + 0];
    xs3[(size_t)v * 4 + 1] = di * node[(size_t)v * 3 + 1];
    xs3[(size_t)v * 4 + 2] = di * node[(size_t)v * 3 + 2];
    xs3[(size_t)v * 4 + 3] = 0.f;
}

// ---------------------------------------------------------------------------
// Conv accumulate: per (partition, split) block. Streams the partition's
// edge slice (coalesced), gathers the src feature (4KB-windowed -> L1),
// accumulates into LDS (stride-7: conflict-free), drains partials.
// FD=3: fp32 [N,4] gathers (conv1). FD=6: fp16 [N,8] gathers.
// ---------------------------------------------------------------------------
template <int FD>
__global__ __launch_bounds__(512) void k_conv(const int* __restrict__ pcur,
                                              const unsigned* __restrict__ elist,
                                              const float* __restrict__ xs4,
                                              const __half* __restrict__ xh8,
                                              float* __restrict__ pacc,
                                              int pcap, int pszn) {
    int p = blockIdx.x, s = blockIdx.y, S = gridDim.y;
    int tid = threadIdx.x;
    __shared__ float acc[PLOC * 7];     // 56 KB, stride-7 -> all 32 banks
    for (int t = tid; t < PLOC * 7; t += 512) acc[t] = 0.f;
    __syncthreads();
    int base = p * pcap;
    int n = min(pcur[p] - base, pcap);
    int lo = (int)((long long)n * s / S), hi = (int)((long long)n * (s + 1) / S);
    if constexpr (FD == 3) {
        const float4* x4 = (const float4*)xs4;
        for (int j = base + lo + tid; j < base + hi; j += 512) {
            unsigned ew = elist[j];
            int sv = (int)(ew >> PSH);
            int dl = (int)(ew & PMSK);
            float4 x = x4[sv];
            atomicAdd(&acc[dl * 7 + 0], x.x);
            atomicAdd(&acc[dl * 7 + 1], x.y);
            atomicAdd(&acc[dl * 7 + 2], x.z);
        }
    } else {
        const float4* h4 = (const float4*)xh8;
        for (int j = base + lo + tid; j < base + hi; j += 512) {
            unsigned ew = elist[j];
            int sv = (int)(ew >> PSH);
            int dl = (int)(ew & PMSK);
            float4 raw = h4[sv];
            const __half2* h2 = (const __half2*)&raw;
            float2 p0 = __half22float2(h2[0]);
            float2 p1 = __half22float2(h2[1]);
            float2 p2 = __half22float2(h2[2]);
            atomicAdd(&acc[dl * 7 + 0], p0.x);
            atomicAdd(&acc[dl * 7 + 1], p0.y);
            atomicAdd(&acc[dl * 7 + 2], p1.x);
            atomicAdd(&acc[dl * 7 + 3], p1.y);
            atomicAdd(&acc[dl * 7 + 4], p2.x);
            atomicAdd(&acc[dl * 7 + 5], p2.y);
        }
    }
    __syncthreads();
    float* dst = pacc + ((size_t)s * pszn + ((size_t)p << PSH)) * 6;
    for (int t = tid; t < PLOC * 6; t += 512) {
        int dl = t / 6, f = t - dl * 6;
        dst[t] = acc[dl * 7 + f];
    }
}

// ---------------------------------------------------------------------------
// Finalize: per node, sum split partials + self-loop, apply dinv, W;
// MODE 0: conv1 write. MODE 1: LN+residual+relu write. MODE 2: + final FC.
// ---------------------------------------------------------------------------
template <int MODE>
__global__ __launch_bounds__(512) void k_fin(const float* __restrict__ pacc,
                                             const float* __restrict__ dinv,
                                             const float* __restrict__ sqd,
                                             const float* __restrict__ xs,  // MODE0 [N,4] else [N,8]
                                             const float* __restrict__ W,
                                             const float* __restrict__ b,
                                             const float* __restrict__ gamma,
                                             const float* __restrict__ beta,
                                             const float* __restrict__ Wfc,
                                             const float* __restrict__ bfc,
                                             float* __restrict__ xsout,
                                             __half* __restrict__ xhout,
                                             float* __restrict__ outfc,
                                             int N, int pszn, int S) {
    constexpr int F = (MODE == 0) ? 3 : 6;
    int v = blockIdx.x * 512 + threadIdx.x;
    if (v >= N) return;
    float a[6] = {0.f, 0.f, 0.f, 0.f, 0.f, 0.f};
    for (int s = 0; s < S; ++s) {
        const float* row = pacc + ((size_t)s * pszn + v) * 6;
#pragma unroll
        for (int f = 0; f < F; ++f) a[f] += row[f];
    }
    float di = dinv[v];
    float xr[6] = {0.f, 0.f, 0.f, 0.f, 0.f, 0.f};
    if constexpr (MODE == 0) {
        float4 srow = ((const float4*)xs)[v];
        a[0] += srow.x; a[1] += srow.y; a[2] += srow.z;
    } else {
        const float* rp = xs + (size_t)v * 8;
        float4 s0 = *(const float4*)rp;
        float2 s1 = *(const float2*)(rp + 4);
        xr[0] = s0.x; xr[1] = s0.y; xr[2] = s0.z;
        xr[3] = s0.w; xr[4] = s1.x; xr[5] = s1.y;
#pragma unroll
        for (int f = 0; f < 6; ++f) a[f] += xr[f];
    }
    float t[F];
#pragma unroll
    for (int f = 0; f < F; ++f) t[f] = di * a[f];
    float y[6];
#pragma unroll
    for (int j = 0; j < 6; ++j) {
        float acc2 = b[j];
#pragma unroll
        for (int k = 0; k < F; ++k) acc2 += t[k] * W[k * 6 + j];
        y[j] = acc2;
    }
    if constexpr (MODE == 0) {
        float* o = xsout + (size_t)v * 8;
        *(float4*)o = make_float4(di * y[0], di * y[1], di * y[2], di * y[3]);
        *(float2*)(o + 4) = make_float2(di * y[4], di * y[5]);
        __half2* oh = (__half2*)(xhout + (size_t)v * 8);
        oh[0] = __floats2half2_rn(di * y[0], di * y[1]);
        oh[1] = __floats2half2_rn(di * y[2], di * y[3]);
        oh[2] = __floats2half2_rn(di * y[4], di * y[5]);
        oh[3] = __floats2half2_rn(0.f, 0.f);
    } else {
        float mu = 0.f;
#pragma unroll
        for (int j = 0; j < 6; ++j) mu += y[j];
        mu *= (1.f / 6.f);
        float var = 0.f;
#pragma unroll
        for (int j = 0; j < 6; ++j) { float dl = y[j] - mu; var += dl * dl; }
        var *= (1.f / 6.f);
        float rs = rsqrtf(var + EPSLN);
        float sq = sqd[v];
        float r[6];
#pragma unroll
        for (int j = 0; j < 6; ++j) {
            float z = (y[j] - mu) * rs * gamma[j] + beta[j] + xr[j] * sq;
            r[j] = z > 0.f ? z : 0.f;
        }
        if constexpr (MODE == 1) {
            float* o = xsout + (size_t)v * 8;
            *(float4*)o = make_float4(di * r[0], di * r[1], di * r[2], di * r[3]);
            *(float2*)(o + 4) = make_float2(di * r[4], di * r[5]);
            __half2* oh = (__half2*)(xhout + (size_t)v * 8);
            oh[0] = __floats2half2_rn(di * r[0], di * r[1]);
            oh[1] = __floats2half2_rn(di * r[2], di * r[3]);
            oh[2] = __floats2half2_rn(di * r[4], di * r[5]);
            oh[3] = __floats2half2_rn(0.f, 0.f);
        } else {
#pragma unroll
            for (int j = 0; j < 3; ++j) {
                float acc2 = bfc[j];
#pragma unroll
                for (int k = 0; k < 6; ++k) acc2 += r[k] * Wfc[k * 3 + j];
                outfc[(size_t)v * 3 + j] = acc2;
            }
        }
    }
}

// ---------------------------------------------------------------------------
extern "C" void kernel_launch(void* const* d_in, const int* in_sizes, int n_in,
                              void* d_out, int out_size, void* d_ws, size_t ws_size,
                              hipStream_t stream) {
    const float* node  = (const float*)d_in[0];
    const int*   edges = (const int*)d_in[1];
    const float* W1    = (const float*)d_in[2];
    const float* b1    = (const float*)d_in[3];
    const float* Wl    = (const float*)d_in[4];
    const float* bl    = (const float*)d_in[5];
    const float* gamma = (const float*)d_in[6];
    const float* beta  = (const float*)d_in[7];
    const float* Wfc   = (const float*)d_in[8];
    const float* bfc   = (const float*)d_in[9];
    float* out = (float*)d_out;

    const int N     = in_sizes[0] / 3;
    const int E     = in_sizes[1] / 2;
    const int STEPS = in_sizes[4] / 36;
    const int* src = edges;
    const int* dst = edges + E;
    const int B = (N + NPB - 1) / NPB;       // src buckets
    const int PCNT = (N + PLOC - 1) >> PSH;  // dst partitions (98 @ N=200000)
    const int PSZN = PCNT << PSH;

    // Coarse bucket capacity: mean + ~8 sigma, 256-aligned, clamped
    const int mean = E / B;
    int CAP = (mean + 8 * (int)(sqrt((double)mean) + 1) + 255) & ~255;
    if (CAP > FCAP) CAP = FCAP;
    // Partition capacity: mean + ~8 sigma, 256-aligned
    const int pmean = E / PCNT;
    const int PCAP = (pmean + 8 * (int)(sqrt((double)pmean) + 1) + 255) & ~255;

    char* ws = (char*)d_ws;
    size_t off = 0;
    auto alloc = [&](size_t bytes) -> void* {
        void* p = ws + off;
        off += (bytes + 255) & ~(size_t)255;
        return p;
    };
    int*      bcur   = (int*)alloc((size_t)B * sizeof(int));
    int*      pcur   = (int*)alloc((size_t)PCNT * sizeof(int));
    float*    dinv   = (float*)alloc((size_t)N * sizeof(float));
    float*    sqd    = (float*)alloc((size_t)N * sizeof(float));
    float*    xs3    = (float*)alloc((size_t)N * 4 * sizeof(float));
    float*    xsa    = (float*)alloc((size_t)N * 8 * sizeof(float));
    float*    xsb    = (float*)alloc((size_t)N * 8 * sizeof(float));
    __half*   xha    = (__half*)alloc((size_t)N * 8 * sizeof(__half));
    __half*   xhb    = (__half*)alloc((size_t)N * 8 * sizeof(__half));
    unsigned* elist  = (unsigned*)alloc((size_t)PCNT * PCAP * sizeof(unsigned));
    unsigned* packed = (unsigned*)alloc((size_t)B * CAP * sizeof(unsigned));
    // pdeg/pacc alias the packed buffer (dead after k_fine); disjoint ranges.
    int*      pdeg   = (int*)packed;
    float*    pacc   = (float*)((char*)packed + (size_t)NSPL * PSZN * sizeof(int));
    (void)ws_size;

    const int gS = (E + TILE - 1) / TILE;
    const int gN = (N + 511) / 512;
    const dim3 gP(PCNT, NSPL);

    k_init<<<(max(B, PCNT) + 511) / 512, 512, 0, stream>>>(bcur, B, CAP, pcur, PCNT, PCAP);
    k_scatter<<<gS, 512, 0, stream>>>(src, dst, bcur, packed, E, B);
    k_fine<<<B, 512, 0, stream>>>(bcur, packed, elist, pcur, CAP, PCAP, PCNT);
    k_deg<<<gP, 512, 0, stream>>>(pcur, elist, pdeg, PCAP, PSZN);
    k_fdeg<<<gN, 512, 0, stream>>>(pdeg, node, dinv, sqd, xs3, N, PSZN, NSPL);

    // Conv 1 (F=3)
    k_conv<3><<<gP, 512, 0, stream>>>(pcur, elist, xs3, nullptr, pacc, PCAP, PSZN);
    k_fin<0><<<gN, 512, 0, stream>>>(pacc, dinv, sqd, xs3, W1, b1,
                                     nullptr, nullptr, nullptr, nullptr,
                                     xsa, xha, nullptr, N, PSZN, NSPL);

    float* xscur = xsa;   __half* xhcur = xha;
    float* xsnxt = xsb;   __half* xhnxt = xhb;
    for (int i = 0; i < STEPS; ++i) {
        const float* W  = Wl + (size_t)i * 36;
        const float* bb = bl + (size_t)i * 6;
        const float* g  = gamma + (size_t)i * 6;
        const float* be = beta + (size_t)i * 6;
        k_conv<6><<<gP, 512, 0, stream>>>(pcur, elist, nullptr, xhcur, pacc, PCAP, PSZN);
        if (i == STEPS - 1) {
            k_fin<2><<<gN, 512, 0, stream>>>(pacc, dinv, sqd, xscur, W, bb, g, be,
                                             Wfc, bfc, nullptr, nullptr, out, N, PSZN, NSPL);
        } else {
            k_fin<1><<<gN, 512, 0, stream>>>(pacc, dinv, sqd, xscur, W, bb, g, be,
                                             nullptr, nullptr, xsnxt, xhnxt, nullptr, N, PSZN, NSPL);
        }
        float* t1 = xscur; xscur = xsnxt; xsnxt = t1;
        __half* t2 = xhcur; xhcur = xhnxt; xhnxt = t2;
    }
}

// Round 5
// 582.246 us; speedup vs baseline: 4.4831x; 4.4831x over previous
//
#include <hip/hip_runtime.h>
#include <hip/hip_fp16.h>
#include <cstdint>

#define EPSLN 1e-5f
#define NPB 256          // nodes per bucket (power of 2)
#define NPB_SHIFT 8
#define MAXB 1024        // max buckets (N <= 262144)
#define TILE 16384       // edges per sort tile (LDS staging = 64KB)
#define SRC_BITS 18      // src id fits 18 bits (N <= 262144)
#define SRC_MASK 0x3FFFF
#define FCAP 17664       // k_fine LDS staging words; >= CAP (mean+8sigma, 256-aligned)
#define FK 35            // FCAP / 512 rounded up

// ---------------------------------------------------------------------------
// Init per-bucket global cursors to fixed-capacity bases: bcur[b] = b*CAP
// ---------------------------------------------------------------------------
__global__ __launch_bounds__(512) void k_init(int* __restrict__ bcur, int B, int cap) {
    int b = blockIdx.x * 512 + threadIdx.x;
    if (b < B) bcur[b] = b * cap;
}

// ---------------------------------------------------------------------------
// Single-pass rank-based scatter: one LDS atomic per edge yields (bucket,
// rank); placement atomic-free. Phase D drains buckets with 16-LANE GROUPS
// (4 buckets/wave concurrently): avg bucket = ~21 words, so 64-lane drains
// idled 2/3 of lanes; 16-lane groups cut Phase-D instruction count ~2.5x.
// ---------------------------------------------------------------------------
__global__ __launch_bounds__(512) void k_scatter(const int* __restrict__ src,
                                                 const int* __restrict__ dst,
                                                 int* __restrict__ bcur,
                                                 unsigned* __restrict__ packed,
                                                 int E, int B) {
    __shared__ unsigned stg[TILE];     // 64 KB staging
    __shared__ int hist[MAXB];         // counts, then reused as gbase
    __shared__ int lbase[MAXB + 1];    // exclusive scan (local segment bases)
    __shared__ int sm[MAXB];           // scan workspace
    int tid = threadIdx.x;
    int i0 = tid, i1 = tid + 512;
    hist[i0] = 0; hist[i1] = 0;
    __syncthreads();

    int beg = blockIdx.x * TILE;
    int end = min(beg + TILE, E);
    int cnt = end - beg;

    unsigned w[32];   // packed payload words
    unsigned m[32];   // meta: (bkt<<14)|rank, 0xFFFFFFFF = invalid

    // Phase A: load + histogram + rank (single pass over src/dst)
    if (cnt == TILE && ((E & 3) == 0)) {
        const int4* d4 = (const int4*)(dst + beg);
        const int4* s4 = (const int4*)(src + beg);
#pragma unroll
        for (int k = 0; k < 8; ++k) {
            int4 d = d4[tid + k * 512];
            int4 s = s4[tid + k * 512];
            int b0 = d.x >> NPB_SHIFT, b1 = d.y >> NPB_SHIFT;
            int b2 = d.z >> NPB_SHIFT, b3 = d.w >> NPB_SHIFT;
            int r0 = atomicAdd(&hist[b0], 1);
            int r1 = atomicAdd(&hist[b1], 1);
            int r2 = atomicAdd(&hist[b2], 1);
            int r3 = atomicAdd(&hist[b3], 1);
            w[4 * k + 0] = ((unsigned)(d.x & (NPB - 1)) << SRC_BITS) | (unsigned)s.x;
            w[4 * k + 1] = ((unsigned)(d.y & (NPB - 1)) << SRC_BITS) | (unsigned)s.y;
            w[4 * k + 2] = ((unsigned)(d.z & (NPB - 1)) << SRC_BITS) | (unsigned)s.z;
            w[4 * k + 3] = ((unsigned)(d.w & (NPB - 1)) << SRC_BITS) | (unsigned)s.w;
            m[4 * k + 0] = ((unsigned)b0 << 14) | (unsigned)r0;
            m[4 * k + 1] = ((unsigned)b1 << 14) | (unsigned)r1;
            m[4 * k + 2] = ((unsigned)b2 << 14) | (unsigned)r2;
            m[4 * k + 3] = ((unsigned)b3 << 14) | (unsigned)r3;
        }
    } else {
#pragma unroll
        for (int k = 0; k < 32; ++k) {
            int i = beg + tid + k * 512;
            if (i < end) {
                int d = dst[i];
                int s = src[i];
                int bkt = d >> NPB_SHIFT;
                int r = atomicAdd(&hist[bkt], 1);
                w[k] = ((unsigned)(d & (NPB - 1)) << SRC_BITS) | (unsigned)s;
                m[k] = ((unsigned)bkt << 14) | (unsigned)r;
            } else {
                m[k] = 0xFFFFFFFFu;
            }
        }
    }
    __syncthreads();

    // Phase B: scan counts -> lbase; reserve global chunks (gbase into hist)
    int v0 = hist[i0], v1 = hist[i1];
    sm[i0] = v0; sm[i1] = v1;
    __syncthreads();
    for (int off = 1; off < MAXB; off <<= 1) {
        int t0 = (i0 >= off) ? sm[i0 - off] : 0;
        int t1 = (i1 >= off) ? sm[i1 - off] : 0;
        __syncthreads();
        sm[i0] += t0; sm[i1] += t1;
        __syncthreads();
    }
    lbase[i0] = sm[i0] - v0;
    lbase[i1] = sm[i1] - v1;
    if (i0 < B) hist[i0] = v0 ? atomicAdd(&bcur[i0], v0) : 0;
    if (i1 < B) hist[i1] = v1 ? atomicAdd(&bcur[i1], v1) : 0;
    if (tid == 0) lbase[B] = cnt;
    __syncthreads();

    // Phase C: place into staging (no atomics; rank precomputed)
#pragma unroll
    for (int k = 0; k < 32; ++k) {
        if (m[k] != 0xFFFFFFFFu) {
            int bkt = (int)(m[k] >> 14);
            int r   = (int)(m[k] & 16383u);
            stg[lbase[bkt] + r] = w[k];
        }
    }
    __syncthreads();

    // Phase D: 16-lane-group bucket drain (4 buckets per wave in parallel;
    // avg bucket ~21 words -> ~85% store-lane efficiency vs ~33% at 64-lane)
    int grp = tid >> 4;          // 0..31
    int gl  = tid & 15;
    for (int b = grp; b < B; b += 32) {
        int lb = lbase[b];
        int le = lbase[b + 1];
        int gb = hist[b];
        for (int j = lb + gl; j < le; j += 16)
            packed[gb + (j - lb)] = stg[j];
    }
}

// ---------------------------------------------------------------------------
// Per-bucket fine sort, LDS-staged (round-3 form, untouched). + fused
// degree/dinv/ptr2/xs3 production.
// ---------------------------------------------------------------------------
__global__ __launch_bounds__(512) void k_fine(const int* __restrict__ bcur,
                                              const unsigned* __restrict__ packed,
                                              int* __restrict__ csr,
                                              int2* __restrict__ ptr2,
                                              float* __restrict__ dinv,
                                              float* __restrict__ sqd,
                                              const float* __restrict__ node,
                                              float* __restrict__ xs3,   // [N,4]
                                              int N, int cap) {
    __shared__ unsigned stg[FCAP];   // ~69 KB sorted-src staging
    __shared__ int hist[NPB];
    __shared__ int exs[NPB];
    int b = blockIdx.x;
    int tid = threadIdx.x;
    int beg = b * cap;
    int cnt = min(bcur[b] - beg, FCAP);
    if (tid < NPB) hist[tid] = 0;
    __syncthreads();

    // Pass A: load bucket words into VGPRs + histogram with rank capture
    unsigned w[FK];
    int r[FK];
#pragma unroll
    for (int k = 0; k < FK; ++k) {
        int i = tid + k * 512;
        if (i < cnt) {
            w[k] = packed[beg + i];
            r[k] = atomicAdd(&hist[w[k] >> SRC_BITS], 1);
        }
    }
    __syncthreads();

    // Pass B: 256-entry scan -> exclusive segment bases; node outputs
    int hv = 0;
    if (tid < NPB) { hv = hist[tid]; exs[tid] = hv; }
    __syncthreads();
    for (int off = 1; off < NPB; off <<= 1) {
        int t = 0;
        if (tid < NPB && tid >= off) t = exs[tid - off];
        __syncthreads();
        if (tid < NPB) exs[tid] += t;
        __syncthreads();
    }
    if (tid < NPB) {
        int ex = exs[tid] - hv;  // exclusive
        int v = b * NPB + tid;
        if (v < N) {
            ptr2[v] = make_int2(beg + ex, beg + ex + hv);
            float c = (float)(hv + 1);      // +1: self-loop
            float di = rsqrtf(c);
            dinv[v] = di;
            sqd[v] = sqrtf(c);              // = 1/di, residual reconstruction
            xs3[(size_t)v * 4 + 0] = di * node[(size_t)v * 3 + 0];
            xs3[(size_t)v * 4 + 1] = di * node[(size_t)v * 3 + 1];
            xs3[(size_t)v * 4 + 2] = di * node[(size_t)v * 3 + 2];
            xs3[(size_t)v * 4 + 3] = 0.f;
        }
        exs[tid] = ex;
    }
    __syncthreads();

    // Pass C: atomic-free LDS scatter into sorted order
#pragma unroll
    for (int k = 0; k < FK; ++k) {
        int i = tid + k * 512;
        if (i < cnt) {
            int dl = (int)(w[k] >> SRC_BITS);
            stg[exs[dl] + r[k]] = w[k] & SRC_MASK;
        }
    }
    __syncthreads();

    // Pass D: linear coalesced drain to global csr
    for (int j = tid; j < cnt; j += 512)
        csr[beg + j] = (int)stg[j];
}

// ---------------------------------------------------------------------------
// Fused conv (round-3 form, untouched): 4 nodes per wave (16-lane segments),
// int2 segment bounds, 4-wide independent gather unroll.
// MODE 0: first conv (F=3, fp32 gathers). MODE 1: mid. MODE 2: final -> out.
// ---------------------------------------------------------------------------
template <int MODE>
__global__ __launch_bounds__(512) void k_conv(const int2* __restrict__ ptr2,
                                              const int* __restrict__ csr,
                                              const float* __restrict__ dinv,
                                              const float* __restrict__ sqd,
                                              const float* __restrict__ xs,   // fp32: MODE0 [N,4], else [N,8]
                                              const __half* __restrict__ xsh, // fp16 [N,8] (MODE1/2)
                                              const float* __restrict__ W,
                                              const float* __restrict__ b,
                                              const float* __restrict__ gamma,
                                              const float* __restrict__ beta,
                                              const float* __restrict__ Wfc,
                                              const float* __restrict__ bfc,
                                              float* __restrict__ xsout,      // fp32 [N,8]
                                              __half* __restrict__ xhout,     // fp16 [N,8]
                                              float* __restrict__ outfc,      // [N,3]
                                              int N) {
    constexpr int F = (MODE == 0) ? 3 : 6;
    int wave = threadIdx.x >> 6;
    int lane = threadIdx.x & 63;
    int sub  = lane >> 4;        // 0..3: which node in this wave
    int li   = lane & 15;        // lane within 16-lane segment
    int v = (blockIdx.x * 8 + wave) * 4 + sub;
    bool valid = v < N;
    int beg = 0, end = 0;
    if (valid) { int2 p = ptr2[v]; beg = p.x; end = p.y; }

    float a0 = 0.f, a1 = 0.f, a2 = 0.f, a3 = 0.f, a4 = 0.f, a5 = 0.f;
    float xr0 = 0.f, xr1 = 0.f, xr2 = 0.f, xr3 = 0.f, xr4 = 0.f, xr5 = 0.f;
    if constexpr (F == 3) {
        const float4* x4 = (const float4*)xs;
        // self-loop issued before the loop (independent load)
        if (valid && li == 0) { float4 p = x4[v]; a0 += p.x; a1 += p.y; a2 += p.z; }
        int i = beg + li;
        int last = end - 1;
        while (i < end) {
            int i1 = i + 16, i2 = i + 32, i3 = i + 48;
            // 4 independent csr loads (clamped; duplicates are mask-dropped)
            int j0 = csr[i];
            int j1 = csr[min(i1, last)];
            int j2 = csr[min(i2, last)];
            int j3 = csr[min(i3, last)];
            // 4 independent gathers in flight
            float4 p0 = x4[j0];
            float4 p1 = x4[j1];
            float4 p2 = x4[j2];
            float4 p3 = x4[j3];
            a0 += p0.x; a1 += p0.y; a2 += p0.z;
            if (i1 < end) { a0 += p1.x; a1 += p1.y; a2 += p1.z; }
            if (i2 < end) { a0 += p2.x; a1 += p2.y; a2 += p2.z; }
            if (i3 < end) { a0 += p3.x; a1 += p3.y; a2 += p3.z; }
            i += 64;
        }
    } else {
        const float4* xh4 = (const float4*)xsh;  // 8 halves = 16B
        if (valid && li == 0) {  // self-loop row loaded ONCE, reused as residual
            const float* rp = xs + (size_t)v * 8;
            float4 p = *(const float4*)rp;
            float2 q = *(const float2*)(rp + 4);
            xr0 = p.x; xr1 = p.y; xr2 = p.z; xr3 = p.w; xr4 = q.x; xr5 = q.y;
            a0 += xr0; a1 += xr1; a2 += xr2; a3 += xr3; a4 += xr4; a5 += xr5;
        }
        int i = beg + li;
        int last = end - 1;
        while (i < end) {
            int i1 = i + 16, i2 = i + 32, i3 = i + 48;
            int j0 = csr[i];
            int j1 = csr[min(i1, last)];
            int j2 = csr[min(i2, last)];
            int j3 = csr[min(i3, last)];
            float4 r0 = xh4[j0];
            float4 r1 = xh4[j1];
            float4 r2 = xh4[j2];
            float4 r3 = xh4[j3];
            {
                const __half2* h2 = (const __half2*)&r0;
                float2 p0 = __half22float2(h2[0]);
                float2 p1 = __half22float2(h2[1]);
                float2 p2 = __half22float2(h2[2]);
                a0 += p0.x; a1 += p0.y; a2 += p1.x; a3 += p1.y; a4 += p2.x; a5 += p2.y;
            }
            if (i1 < end) {
                const __half2* h2 = (const __half2*)&r1;
                float2 p0 = __half22float2(h2[0]);
                float2 p1 = __half22float2(h2[1]);
                float2 p2 = __half22float2(h2[2]);
                a0 += p0.x; a1 += p0.y; a2 += p1.x; a3 += p1.y; a4 += p2.x; a5 += p2.y;
            }
            if (i2 < end) {
                const __half2* h2 = (const __half2*)&r2;
                float2 p0 = __half22float2(h2[0]);
                float2 p1 = __half22float2(h2[1]);
                float2 p2 = __half22float2(h2[2]);
                a0 += p0.x; a1 += p0.y; a2 += p1.x; a3 += p1.y; a4 += p2.x; a5 += p2.y;
            }
            if (i3 < end) {
                const __half2* h2 = (const __half2*)&r3;
                float2 p0 = __half22float2(h2[0]);
                float2 p1 = __half22float2(h2[1]);
                float2 p2 = __half22float2(h2[2]);
                a0 += p0.x; a1 += p0.y; a2 += p1.x; a3 += p1.y; a4 += p2.x; a5 += p2.y;
            }
            i += 64;
        }
    }
#pragma unroll
    for (int off = 8; off >= 1; off >>= 1) {
        a0 += __shfl_down(a0, off);
        a1 += __shfl_down(a1, off);
        a2 += __shfl_down(a2, off);
        if constexpr (F == 6) {
            a3 += __shfl_down(a3, off);
            a4 += __shfl_down(a4, off);
            a5 += __shfl_down(a5, off);
        }
    }
    if (li != 0 || !valid) return;

    float di = dinv[v];
    float t[F];
    t[0] = di * a0; t[1] = di * a1; t[2] = di * a2;
    if constexpr (F == 6) { t[3] = di * a3; t[4] = di * a4; t[5] = di * a5; }

    float y[6];
#pragma unroll
    for (int j = 0; j < 6; ++j) {
        float acc = b[j];
#pragma unroll
        for (int k = 0; k < F; ++k) acc += t[k] * W[k * 6 + j];
        y[j] = acc;
    }

    if constexpr (MODE == 0) {
        float* o = xsout + (size_t)v * 8;
        *(float4*)o = make_float4(di * y[0], di * y[1], di * y[2], di * y[3]);
        *(float2*)(o + 4) = make_float2(di * y[4], di * y[5]);
        __half2* oh = (__half2*)(xhout + (size_t)v * 8);
        oh[0] = __floats2half2_rn(di * y[0], di * y[1]);
        oh[1] = __floats2half2_rn(di * y[2], di * y[3]);
        oh[2] = __floats2half2_rn(di * y[4], di * y[5]);
        oh[3] = __floats2half2_rn(0.f, 0.f);
    } else {
        float mu = 0.f;
#pragma unroll
        for (int j = 0; j < 6; ++j) mu += y[j];
        mu *= (1.f / 6.f);
        float var = 0.f;
#pragma unroll
        for (int j = 0; j < 6; ++j) { float dl = y[j] - mu; var += dl * dl; }
        var *= (1.f / 6.f);
        float rs = rsqrtf(var + EPSLN);
        float sq = sqd[v];
        float xr[6] = {xr0, xr1, xr2, xr3, xr4, xr5};  // residual (already loaded)
        float r[6];
#pragma unroll
        for (int j = 0; j < 6; ++j) {
            float z = (y[j] - mu) * rs * gamma[j] + beta[j] + xr[j] * sq;
            r[j] = z > 0.f ? z : 0.f;
        }
        if constexpr (MODE == 1) {
            float* o = xsout + (size_t)v * 8;
            *(float4*)o = make_float4(di * r[0], di * r[1], di * r[2], di * r[3]);
            *(float2*)(o + 4) = make_float2(di * r[4], di * r[5]);
            __half2* oh = (__half2*)(xhout + (size_t)v * 8);
            oh[0] = __floats2half2_rn(di * r[0], di * r[1]);
            oh[1] = __floats2half2_rn(di * r[2], di * r[3]);
            oh[2] = __floats2half2_rn(di * r[4], di * r[5]);
            oh[3] = __floats2half2_rn(0.f, 0.f);
        } else {
#pragma unroll
            for (int j = 0; j < 3; ++j) {
                float acc = bfc[j];
#pragma unroll
                for (int k = 0; k < 6; ++k) acc += r[k] * Wfc[k * 3 + j];
                outfc[(size_t)v * 3 + j] = acc;
            }
        }
    }
}

// ---------------------------------------------------------------------------
extern "C" void kernel_launch(void* const* d_in, const int* in_sizes, int n_in,
                              void* d_out, int out_size, void* d_ws, size_t ws_size,
                              hipStream_t stream) {
    const float* node  = (const float*)d_in[0];
    const int*   edges = (const int*)d_in[1];
    const float* W1    = (const float*)d_in[2];
    const float* b1    = (const float*)d_in[3];
    const float* Wl    = (const float*)d_in[4];
    const float* bl    = (const float*)d_in[5];
    const float* gamma = (const float*)d_in[6];
    const float* beta  = (const float*)d_in[7];
    const float* Wfc   = (const float*)d_in[8];
    const float* bfc   = (const float*)d_in[9];
    float* out = (float*)d_out;

    const int N     = in_sizes[0] / 3;
    const int E     = in_sizes[1] / 2;
    const int STEPS = in_sizes[4] / 36;
    const int* src = edges;
    const int* dst = edges + E;
    const int B = (N + NPB - 1) / NPB;   // 782 for N=200000

    // Fixed bucket capacity: mean + ~8 sigma, 256-aligned, clamped to LDS cap
    const int mean = E / B;
    int CAP = (mean + 8 * (int)(sqrt((double)mean) + 1) + 255) & ~255;
    if (CAP > FCAP) CAP = FCAP;

    char* ws = (char*)d_ws;
    size_t off = 0;
    auto alloc = [&](size_t bytes) -> void* {
        void* p = ws + off;
        off += (bytes + 255) & ~(size_t)255;
        return p;
    };
    int*      bcur   = (int*)alloc((size_t)B * sizeof(int));
    int2*     ptr2   = (int2*)alloc((size_t)N * sizeof(int2));
    float*    dinv   = (float*)alloc((size_t)N * sizeof(float));
    float*    sqd    = (float*)alloc((size_t)N * sizeof(float));
    unsigned* packed = (unsigned*)alloc((size_t)B * CAP * sizeof(unsigned));
    int*      csr    = (int*)alloc((size_t)B * CAP * sizeof(int));
    float*    xs3    = (float*)alloc((size_t)N * 4 * sizeof(float));
    float*    xsa    = (float*)alloc((size_t)N * 8 * sizeof(float));
    float*    xsb    = (float*)alloc((size_t)N * 8 * sizeof(float));
    __half*   xha    = (__half*)alloc((size_t)N * 8 * sizeof(__half));
    __half*   xhb    = (__half*)alloc((size_t)N * 8 * sizeof(__half));
    (void)ws_size;

    const int gS = (E + TILE - 1) / TILE;   // 782
    const int gC = (N + 31) / 32;           // 4 nodes/wave, 8 waves/block

    k_init<<<(B + 511) / 512, 512, 0, stream>>>(bcur, B, CAP);
    k_scatter<<<gS, 512, 0, stream>>>(src, dst, bcur, packed, E, B);
    k_fine<<<B, 512, 0, stream>>>(bcur, packed, csr, ptr2, dinv, sqd, node, xs3, N, CAP);

    // Conv 1 (F=3): xsa/xha = dinv * ((A_hat @ node) @ W1 + b1)
    k_conv<0><<<gC, 512, 0, stream>>>(ptr2, csr, dinv, sqd, xs3, nullptr, W1, b1,
                                      nullptr, nullptr, nullptr, nullptr,
                                      xsa, xha, nullptr, N);

    float* xscur = xsa;   __half* xhcur = xha;
    float* xsnxt = xsb;   __half* xhnxt = xhb;
    for (int i = 0; i < STEPS; ++i) {
        const float* W  = Wl + (size_t)i * 36;
        const float* bb = bl + (size_t)i * 6;
        const float* g  = gamma + (size_t)i * 6;
        const float* be = beta + (size_t)i * 6;
        if (i == STEPS - 1) {
            k_conv<2><<<gC, 512, 0, stream>>>(ptr2, csr, dinv, sqd, xscur, xhcur, W, bb,
                                              g, be, Wfc, bfc, nullptr, nullptr, out, N);
        } else {
            k_conv<1><<<gC, 512, 0, stream>>>(ptr2, csr, dinv, sqd, xscur, xhcur, W, bb,
                                              g, be, nullptr, nullptr, xsnxt, xhnxt, nullptr, N);
        }
        float* t1 = xscur; xscur = xsnxt; xsnxt = t1;
        __half* t2 = xhcur; xhcur = xhnxt; xhnxt = t2;
    }
}